// Round 2
// baseline (2251.198 us; speedup 1.0000x reference)
//
#include <hip/hip_runtime.h>
#include <math.h>

// StrangeAttractor: B=524288 rows, E=128.
//   score[j] = ||c_j||^2 - 2 x.c_j   (== d2[j] - ||x||^2; same argmin order)
//   idx = first argmin_j score      (strict <, numpy first-min semantics)
//   dist = sqrt(max(||x||^2 + best_score, 0))
//   s = 0.1 * exp(-dist / (radii[idx] + 1e-8))
//   attracted = x*(1-s) + c_idx*s
//
// K-split-2 layout: lanes 2i/2i+1 handle the SAME row; even lane owns
// k=[0,64), odd lane owns k=[64,128). Per-center partial dots combined with
// one shfl_xor(1); p+q is commutative -> bit-identical in both lanes ->
// identical argmin, zero divergence.
//
// This revision: 4 centers per j-block (2 accumulators each, 4 float4
// c-temps per k-step) to keep peak VGPR liveness < 128 so
// __launch_bounds__(256,4) (4 waves/SIMD) holds without scratch spills,
// and to batch the 4 shfl_xor combines per block.

#define BATCH 524288
#define E 128
#define HALF 64

__global__ void csq_kernel(const float* __restrict__ c, float* __restrict__ csq) {
    int j = threadIdx.x;  // 128 threads, 1 block
    const float* cj = c + j * E;
    float a0 = 0.f, a1 = 0.f, a2 = 0.f, a3 = 0.f;
#pragma unroll
    for (int k = 0; k < E; k += 4) {
        a0 = fmaf(cj[k + 0], cj[k + 0], a0);
        a1 = fmaf(cj[k + 1], cj[k + 1], a1);
        a2 = fmaf(cj[k + 2], cj[k + 2], a2);
        a3 = fmaf(cj[k + 3], cj[k + 3], a3);
    }
    csq[j] = (a0 + a1) + (a2 + a3);
}

__global__ __launch_bounds__(256, 4) void attractor_kernel(
        const float* __restrict__ xin,
        const float* __restrict__ c,
        const float* __restrict__ radii,
        const float* __restrict__ csq,
        float* __restrict__ out_attr,
        float* __restrict__ out_idx) {
    const int tid = blockIdx.x * blockDim.x + threadIdx.x;
    const int row = tid >> 1;
    const int h   = tid & 1;  // which k-half this lane owns

    // ---- load my half-row (64 floats, 16 x dwordx4). Wave reads 16 KB
    // contiguous -> fully coalesced. ----
    const float4* x4 = reinterpret_cast<const float4*>(
        xin + (size_t)row * E + h * HALF);
    float x[HALF];
#pragma unroll
    for (int k = 0; k < HALF / 4; ++k) {
        float4 v = x4[k];
        x[4 * k + 0] = v.x;
        x[4 * k + 1] = v.y;
        x[4 * k + 2] = v.z;
        x[4 * k + 3] = v.w;
    }

    // ---- partial ||x||^2 over my half ----
    float s0 = 0.f, s1 = 0.f, s2 = 0.f, s3 = 0.f;
#pragma unroll
    for (int k = 0; k < HALF; k += 4) {
        s0 = fmaf(x[k + 0], x[k + 0], s0);
        s1 = fmaf(x[k + 1], x[k + 1], s1);
        s2 = fmaf(x[k + 2], x[k + 2], s2);
        s3 = fmaf(x[k + 3], x[k + 3], s3);
    }
    const float xsq_half = (s0 + s1) + (s2 + s3);

    // ---- main loop: 4 centers per block, running first-argmin on score ----
    float best_score = 3.4e38f;
    int best_j = 0;
    const float4* cb4 = reinterpret_cast<const float4*>(c + h * HALF);
#pragma unroll 1
    for (int j = 0; j < E; j += 4) {
        const float4* cp0 = cb4 + (size_t)(j + 0) * (E / 4);
        const float4* cp1 = cb4 + (size_t)(j + 1) * (E / 4);
        const float4* cp2 = cb4 + (size_t)(j + 2) * (E / 4);
        const float4* cp3 = cb4 + (size_t)(j + 3) * (E / 4);
        // 2 accumulators per center (k-parity split): 8 independent FMA
        // chains; per k-step only 4 float4 c-values live.
        float a0 = 0.f, a1 = 0.f;
        float b0 = 0.f, b1 = 0.f;
        float e0 = 0.f, e1 = 0.f;
        float f0 = 0.f, f1 = 0.f;
#pragma unroll
        for (int k = 0; k < HALF / 4; ++k) {
            const float xk0 = x[4 * k + 0];
            const float xk1 = x[4 * k + 1];
            const float xk2 = x[4 * k + 2];
            const float xk3 = x[4 * k + 3];
            float4 u0 = cp0[k];
            float4 u1 = cp1[k];
            float4 u2 = cp2[k];
            float4 u3 = cp3[k];
            a0 = fmaf(xk0, u0.x, a0); a1 = fmaf(xk1, u0.y, a1);
            a0 = fmaf(xk2, u0.z, a0); a1 = fmaf(xk3, u0.w, a1);
            b0 = fmaf(xk0, u1.x, b0); b1 = fmaf(xk1, u1.y, b1);
            b0 = fmaf(xk2, u1.z, b0); b1 = fmaf(xk3, u1.w, b1);
            e0 = fmaf(xk0, u2.x, e0); e1 = fmaf(xk1, u2.y, e1);
            e0 = fmaf(xk2, u2.z, e0); e1 = fmaf(xk3, u2.w, e1);
            f0 = fmaf(xk0, u3.x, f0); f1 = fmaf(xk1, u3.y, f1);
            f0 = fmaf(xk2, u3.z, f0); f1 = fmaf(xk3, u3.w, f1);
        }
        const float p0 = a0 + a1;
        const float p1 = b0 + b1;
        const float p2 = e0 + e1;
        const float p3 = f0 + f1;
        // combine k-halves across the lane pair; 4 independent shfls issue
        // back-to-back (overlapped lgkm waits). Commutative add ->
        // bit-identical in both lanes.
        const float q0 = __shfl_xor(p0, 1, 64);
        const float q1 = __shfl_xor(p1, 1, 64);
        const float q2 = __shfl_xor(p2, 1, 64);
        const float q3 = __shfl_xor(p3, 1, 64);
        const float sc0 = fmaf(-2.0f, p0 + q0, csq[j + 0]);
        const float sc1 = fmaf(-2.0f, p1 + q1, csq[j + 1]);
        const float sc2 = fmaf(-2.0f, p2 + q2, csq[j + 2]);
        const float sc3 = fmaf(-2.0f, p3 + q3, csq[j + 3]);
        // ordered strict < keeps the FIRST minimum (numpy argmin semantics)
        if (sc0 < best_score) { best_score = sc0; best_j = j + 0; }
        if (sc1 < best_score) { best_score = sc1; best_j = j + 1; }
        if (sc2 < best_score) { best_score = sc2; best_j = j + 2; }
        if (sc3 < best_score) { best_score = sc3; best_j = j + 3; }
    }

    // ---- epilogue: blend toward chosen center ----
    const float xsq = xsq_half + __shfl_xor(xsq_half, 1, 64);
    const float d2 = xsq + best_score;
    const float dist = sqrtf(fmaxf(d2, 0.0f));
    const float r = radii[best_j];
    const float strength = __expf(-dist / (r + 1e-8f));
    const float s = 0.1f * strength;
    const float oms = 1.0f - s;

    const float4* cbl = reinterpret_cast<const float4*>(
        c + (size_t)best_j * E + h * HALF);  // 64 KB table, L2-hot gather
    float4* o4 = reinterpret_cast<float4*>(
        out_attr + (size_t)row * E + h * HALF);
#pragma unroll
    for (int k = 0; k < HALF / 4; ++k) {
        float4 cv = cbl[k];
        float4 v;
        v.x = x[4 * k + 0] * oms + cv.x * s;
        v.y = x[4 * k + 1] * oms + cv.y * s;
        v.z = x[4 * k + 2] * oms + cv.z * s;
        v.w = x[4 * k + 3] * oms + cv.w * s;
        o4[k] = v;
    }
    if (h == 0) out_idx[row] = (float)best_j;
}

extern "C" void kernel_launch(void* const* d_in, const int* in_sizes, int n_in,
                              void* d_out, int out_size, void* d_ws, size_t ws_size,
                              hipStream_t stream) {
    const float* x     = (const float*)d_in[0];  // [B, E]
    const float* c     = (const float*)d_in[1];  // [E, E]
    const float* radii = (const float*)d_in[2];  // [E]

    float* out_attr = (float*)d_out;                      // [B*E]
    float* out_idx  = (float*)d_out + (size_t)BATCH * E;  // [B] as float
    float* csq      = (float*)d_ws;                       // [E]

    csq_kernel<<<1, E, 0, stream>>>(c, csq);
    // 2 lanes per row -> 2*B threads
    attractor_kernel<<<(2 * BATCH) / 256, 256, 0, stream>>>(
        x, c, radii, csq, out_attr, out_idx);
}